// Round 3
// baseline (669.084 us; speedup 1.0000x reference)
//
#include <hip/hip_runtime.h>
#include <hip/hip_bf16.h>
#include <cstdint>
#include <cstddef>

typedef __attribute__((ext_vector_type(8))) short short8;
typedef __attribute__((ext_vector_type(4))) float f32x4;

#define AS1U32(p) ((const __attribute__((address_space(1))) uint32_t*)(p))
#define AS3U32(p) ((__attribute__((address_space(3))) uint32_t*)(p))

__device__ __forceinline__ unsigned short f2bf(float v) {
  union { float f; uint32_t u; } a; a.f = v;
  uint32_t u = a.u;
  u += 0x7FFFu + ((u >> 16) & 1u);   // round-to-nearest-even
  return (unsigned short)(u >> 16);
}

// gelu(x) = x * sigmoid(2u), u = sqrt(2/pi)(x + 0.044715 x^3); rcp instead of div
__device__ __forceinline__ float gelu_fast(float x) {
  const float c0 = 0.7978845608028654f;
  const float c1 = 0.044715f;
  float u = c0 * (x + c1 * x * x * x);
  return x * __builtin_amdgcn_rcpf(1.0f + __expf(-2.0f * u));
}

// ---------------- prologue kernels ----------------

__global__ __launch_bounds__(512)
void reduce_x(const float* __restrict__ x, float* __restrict__ ksum) {
  const int d = threadIdx.x;
  float s = 0.f;
  for (int t = blockIdx.x; t < 16384; t += gridDim.x)
    s += x[(size_t)t * 512 + d];
  atomicAdd(&ksum[d], s);
}

__global__ void gate_topk(const float* __restrict__ gate_w,
                          const float* __restrict__ gate_b,
                          const float* __restrict__ ksum,
                          int* __restrict__ idxout) {
  const int lane = threadIdx.x;  // 64 threads
  __shared__ float coarse[16];
  for (int e = 0; e < 16; e++) {
    float s = 0.f;
    for (int d = lane; d < 512; d += 64) s += gate_w[e * 512 + d] * ksum[d];
#pragma unroll
    for (int off = 32; off >= 1; off >>= 1) s += __shfl_down(s, off, 64);
    if (lane == 0) coarse[e] = s + gate_b[e];
  }
  if (lane == 0) {
    unsigned taken = 0;
    for (int r = 0; r < 4; r++) {
      float best = -3.4e38f; int bi = 0;
      for (int e = 0; e < 16; e++)
        if (!((taken >> e) & 1u) && coarse[e] > best) { best = coarse[e]; bi = e; }
      taken |= 1u << bi;
      idxout[r] = bi;
    }
  }
}

__global__ void bias_gather(const float* __restrict__ b1, const float* __restrict__ b2,
                            const int* __restrict__ idx,
                            float* __restrict__ b1cat, float* __restrict__ b2sel) {
  int i = blockIdx.x * 256 + threadIdx.x;
  if (i < 8192) b1cat[i] = b1[(size_t)idx[i >> 11] * 2048 + (i & 2047)];
  if (i < 2048) b2sel[i] = b2[(size_t)idx[i >> 9] * 512 + (i & 511)];
}

// transpose + fp32->bf16: src [R x C] row-major at idx[e]; dst[(e*expertOff) + c*dstLd + r]
__global__ __launch_bounds__(256)
void transpose_conv(const float* __restrict__ src, unsigned short* __restrict__ dst,
                    const int* __restrict__ idx, int R, int C, int dstLd,
                    size_t expertOff) {
  __shared__ float tl[64][65];
  const int tid = threadIdx.x;
  const int ty = tid >> 6, tx = tid & 63;
  const int r0 = blockIdx.x * 64, c0 = blockIdx.y * 64;
  const int e = blockIdx.z;
  const float* s = src + (size_t)idx[e] * (size_t)R * (size_t)C;
#pragma unroll
  for (int i = 0; i < 16; i++) {
    int r = ty * 16 + i;
    tl[r][tx] = s[(size_t)(r0 + r) * C + c0 + tx];
  }
  __syncthreads();
  unsigned short* dbase = dst + (size_t)e * expertOff;
#pragma unroll
  for (int i = 0; i < 16; i++) {
    int rr = ty * 16 + i;
    dbase[(size_t)(c0 + rr) * dstLd + r0 + tx] = f2bf(tl[tx][rr]);
  }
}

// per-token softmax gate over 4 selected experts + x -> bf16
__global__ __launch_bounds__(256)
void gate_softmax_xconv(const float* __restrict__ x,
                        const float* __restrict__ gate_w,
                        const float* __restrict__ gate_b,
                        const int* __restrict__ idx,
                        float* __restrict__ gwout,
                        unsigned short* __restrict__ xbf) {
  __shared__ float wsel[4][512];
  __shared__ float bsel[4];
  const int tid = threadIdx.x;
  for (int i = tid; i < 2048; i += 256) {
    int k = i >> 9;
    wsel[k][i & 511] = gate_w[(size_t)idx[k] * 512 + (i & 511)];
  }
  if (tid < 4) bsel[tid] = gate_b[idx[tid]];
  __syncthreads();
  const int wave = tid >> 6, lane = tid & 63;
  const int t = blockIdx.x * 4 + wave;
  const float* xr = x + (size_t)t * 512 + lane * 8;
  float4 v0 = ((const float4*)xr)[0];
  float4 v1 = ((const float4*)xr)[1];
  float vals[8] = {v0.x, v0.y, v0.z, v0.w, v1.x, v1.y, v1.z, v1.w};
  short8 pk;
#pragma unroll
  for (int j = 0; j < 8; j++) pk[j] = (short)f2bf(vals[j]);
  *(short8*)(xbf + (size_t)t * 512 + lane * 8) = pk;
  float a0 = 0.f, a1 = 0.f, a2 = 0.f, a3 = 0.f;
  const int dbase = lane * 8;
#pragma unroll
  for (int j = 0; j < 8; j++) {
    float xv = vals[j];
    a0 += xv * wsel[0][dbase + j];
    a1 += xv * wsel[1][dbase + j];
    a2 += xv * wsel[2][dbase + j];
    a3 += xv * wsel[3][dbase + j];
  }
#pragma unroll
  for (int off = 32; off >= 1; off >>= 1) {
    a0 += __shfl_down(a0, off, 64);
    a1 += __shfl_down(a1, off, 64);
    a2 += __shfl_down(a2, off, 64);
    a3 += __shfl_down(a3, off, 64);
  }
  if (lane == 0) {
    float l0 = a0 + bsel[0], l1 = a1 + bsel[1], l2 = a2 + bsel[2], l3 = a3 + bsel[3];
    float m = fmaxf(fmaxf(l0, l1), fmaxf(l2, l3));
    float e0 = __expf(l0 - m), e1 = __expf(l1 - m);
    float e2 = __expf(l2 - m), e3 = __expf(l3 - m);
    float inv = 1.0f / (e0 + e1 + e2 + e3);
    float* o = gwout + (size_t)t * 4;
    o[0] = e0 * inv; o[1] = e1 * inv; o[2] = e2 * inv; o[3] = e3 * inv;
  }
}

// ---------------- main GEMM ----------------
// C[M x N] = A[M x K(lda)] * Bt[N x K(ldb)]^T  (bf16, K-contiguous rows)
// 128x128 tile, BK=64, 256 threads, 16x16x32 bf16 MFMA, XOR-swizzled LDS.
// EPI==1: Cb[r*ldc+n] = bf16( gw[r,kexp] * gelu(acc + bias[colOff+n]) ),
//         kexp = (colOff+rowB0)>>11
// EPI==2: Cf[r*512+n] = acc + (accum ? Cf[r*512+n]
//                                    : sum_k gw[r,k]*bias[k*512+n])
template <int EPI>
__global__ __launch_bounds__(256, 2)
void gemm_bt(const unsigned short* __restrict__ A,
             const unsigned short* __restrict__ Bt,
             void* __restrict__ C, int K, int lda, int ldb, int ldc,
             const float* __restrict__ gw,
             const float* __restrict__ bias, int colOff, int accum) {
  __shared__ unsigned short lA[128 * 64];
  __shared__ unsigned short lB[128 * 64];
  const int tid = threadIdx.x;
  const int wave = tid >> 6;
  const int lane = tid & 63;
  const int rowA0 = blockIdx.x * 128;
  const int rowB0 = blockIdx.y * 128;

  f32x4 acc[4][4];
#pragma unroll
  for (int i = 0; i < 4; i++)
#pragma unroll
    for (int j = 0; j < 4; j++) acc[i][j] = (f32x4){0.f, 0.f, 0.f, 0.f};

  const int lrow = lane >> 3;
  const int lslot = lane & 7;
  const int gchunk = lslot ^ lrow;     // store-side XOR swizzle (16B granule)
  const int fr = lane & 15;
  const int quad = lane >> 4;
  const int wm = (wave >> 1) * 64;
  const int wn = (wave & 1) * 64;
  const int swz = fr & 7;

  for (int kt = 0; kt < K; kt += 64) {
#pragma unroll
    for (int c = 0; c < 4; c++) {
      int r = wave * 32 + c * 8 + lrow;
      const unsigned short* gp = A + (size_t)(rowA0 + r) * lda + kt + gchunk * 8;
      __builtin_amdgcn_global_load_lds(AS1U32(gp), AS3U32(lA + (wave * 32 + c * 8) * 64), 16, 0, 0);
    }
#pragma unroll
    for (int c = 0; c < 4; c++) {
      int r = wave * 32 + c * 8 + lrow;
      const unsigned short* gp = Bt + (size_t)(rowB0 + r) * ldb + kt + gchunk * 8;
      __builtin_amdgcn_global_load_lds(AS1U32(gp), AS3U32(lB + (wave * 32 + c * 8) * 64), 16, 0, 0);
    }
    __syncthreads();
#pragma unroll
    for (int ks = 0; ks < 2; ks++) {
      short8 af[4], bfr[4];
      const int c = ks * 4 + quad;
      const int slot = (c ^ swz) << 3;
#pragma unroll
      for (int i = 0; i < 4; i++)
        af[i] = *(const short8*)(lA + (wm + i * 16 + fr) * 64 + slot);
#pragma unroll
      for (int j = 0; j < 4; j++)
        bfr[j] = *(const short8*)(lB + (wn + j * 16 + fr) * 64 + slot);
#pragma unroll
      for (int i = 0; i < 4; i++)
#pragma unroll
        for (int j = 0; j < 4; j++)
          acc[i][j] = __builtin_amdgcn_mfma_f32_16x16x32_bf16(af[i], bfr[j], acc[i][j], 0, 0, 0);
    }
    __syncthreads();
  }

  // epilogue: C/D layout col=lane&15, row=quad*4+reg (m89/m91-verified)
  if (EPI == 1) {
    unsigned short* Cb = (unsigned short*)C;
    const int kexp = (colOff + rowB0) >> 11;
#pragma unroll
    for (int i = 0; i < 4; i++) {
#pragma unroll
      for (int reg = 0; reg < 4; reg++) {
        int r = rowA0 + wm + i * 16 + quad * 4 + reg;
        float g = gw[(size_t)r * 4 + kexp];
#pragma unroll
        for (int j = 0; j < 4; j++) {
          int n = rowB0 + wn + j * 16 + fr;
          float v = acc[i][j][reg] + bias[colOff + n];
          Cb[(size_t)r * ldc + n] = f2bf(gelu_fast(v) * g);
        }
      }
    }
  } else {
    float* Cf = (float*)C;
#pragma unroll
    for (int i = 0; i < 4; i++) {
#pragma unroll
      for (int reg = 0; reg < 4; reg++) {
        int r = rowA0 + wm + i * 16 + quad * 4 + reg;
        size_t t4 = (size_t)r * 4;
        float g0 = gw[t4], g1 = gw[t4 + 1], g2 = gw[t4 + 2], g3 = gw[t4 + 3];
#pragma unroll
        for (int j = 0; j < 4; j++) {
          int n = rowB0 + wn + j * 16 + fr;
          size_t ci = (size_t)r * 512 + n;
          float v = acc[i][j][reg];
          if (accum) v += Cf[ci];
          else v += g0 * bias[n] + g1 * bias[512 + n] +
                    g2 * bias[1024 + n] + g3 * bias[1536 + n];
          Cf[ci] = v;
        }
      }
    }
  }
}

// ---------------- launch ----------------

extern "C" void kernel_launch(void* const* d_in, const int* in_sizes, int n_in,
                              void* d_out, int out_size, void* d_ws, size_t ws_size,
                              hipStream_t stream) {
  (void)in_sizes; (void)n_in; (void)out_size;
  const float* x      = (const float*)d_in[0];
  const float* gate_w = (const float*)d_in[1];
  const float* gate_b = (const float*)d_in[2];
  const float* w1     = (const float*)d_in[3];
  const float* b1     = (const float*)d_in[4];
  const float* w2     = (const float*)d_in[5];
  const float* b2     = (const float*)d_in[6];

  char* ws = (char*)d_ws;
  float*          ksum  = (float*)(ws + 0);              //   2 KB
  int*            idx   = (int*)(ws + 2048);             //  16 B
  float*          gw    = (float*)(ws + 4096);           // 256 KB  [T,4]
  float*          b1cat = (float*)(ws + 266240);         //  32 KB  [8192]
  float*          b2sel = (float*)(ws + 299008);         //   8 KB  [4,512]
  unsigned short* xbf   = (unsigned short*)(ws + 307200);      // 16 MB [T,512]
  unsigned short* w1t   = (unsigned short*)(ws + 17084416);    //  8 MB [8192,512]
  unsigned short* w2t   = (unsigned short*)(ws + 25473024);    //  8 MB [512,8192]
  unsigned short* hbuf  = (unsigned short*)(ws + 33861632);    // h' slab
  const size_t HBUF_OFF = 33861632;

  // DF-slab sized for LLC residency: h' slab = 16384 x slabDF bf16.
  // nslab=4 -> 67 MB slab; phase working set ~134 MB < 256 MB Infinity Cache,
  // so GEMM1's write -> GEMM2's 4x re-read cycles through LLC, not HBM.
  size_t avail = ws_size > HBUF_OFF ? ws_size - HBUF_OFF : 0;
  int nslab = 4;
  while (nslab < 16 && (size_t)16384 * (8192 / nslab) * 2 > avail) nslab <<= 1;
  const int slabDF = 8192 / nslab;

  hipMemsetAsync(ksum, 0, 2048, stream);
  reduce_x<<<256, 512, 0, stream>>>(x, ksum);
  gate_topk<<<1, 64, 0, stream>>>(gate_w, gate_b, ksum, idx);
  bias_gather<<<40, 256, 0, stream>>>(b1, b2, idx, b1cat, b2sel);
  // W1: [512 x 2048] per expert -> w1t[(k*2048+f)*512 + d]
  transpose_conv<<<dim3(8, 32, 4), 256, 0, stream>>>(w1, w1t, idx, 512, 2048, 512, (size_t)2048 * 512);
  // W2: [2048 x 512] per expert -> w2t[d*8192 + k*2048 + f]
  transpose_conv<<<dim3(32, 8, 4), 256, 0, stream>>>(w2, w2t, idx, 2048, 512, 8192, (size_t)2048);
  gate_softmax_xconv<<<4096, 256, 0, stream>>>(x, gate_w, gate_b, idx, gw, xbf);

  for (int s = 0; s < nslab; s++) {
    const int c0 = s * slabDF;
    // h'[:, c0:c0+slabDF] = bf16(gw * gelu(x @ W1[:, c0:...] + b1))
    gemm_bt<1><<<dim3(128, slabDF / 128), 256, 0, stream>>>(
        xbf, w1t + (size_t)c0 * 512, hbuf,
        /*K=*/512, /*lda=*/512, /*ldb=*/512, /*ldc=*/slabDF,
        gw, b1cat, c0, 0);
    // out (+)= h'slab @ W2[c0:..., :]  (+ gw-weighted b2 on slab 0)
    gemm_bt<2><<<dim3(128, 4), 256, 0, stream>>>(
        hbuf, w2t + c0, (float*)d_out,
        /*K=*/slabDF, /*lda=*/slabDF, /*ldb=*/8192, /*ldc=*/512,
        gw, b2sel, 0, s > 0);
  }
}

// Round 4
// 525.047 us; speedup vs baseline: 1.2743x; 1.2743x over previous
//
#include <hip/hip_runtime.h>
#include <hip/hip_bf16.h>
#include <cstdint>
#include <cstddef>

typedef __attribute__((ext_vector_type(8))) short short8;
typedef __attribute__((ext_vector_type(4))) float f32x4;

#define AS1U32(p) ((const __attribute__((address_space(1))) uint32_t*)(p))
#define AS3U32(p) ((__attribute__((address_space(3))) uint32_t*)(p))

__device__ __forceinline__ unsigned short f2bf(float v) {
  union { float f; uint32_t u; } a; a.f = v;
  uint32_t u = a.u;
  u += 0x7FFFu + ((u >> 16) & 1u);   // round-to-nearest-even
  return (unsigned short)(u >> 16);
}

// gelu(x) = x * sigmoid(2u), u = sqrt(2/pi)(x + 0.044715 x^3)
__device__ __forceinline__ float gelu_fast(float x) {
  const float c0 = 0.7978845608028654f;
  const float c1 = 0.044715f;
  float u = c0 * (x + c1 * x * x * x);
  return x * __builtin_amdgcn_rcpf(1.0f + __expf(-2.0f * u));
}

// ---------------- prologue kernels ----------------

// partial token-sums: kpart[b*512+d] = sum_{i<64} x[(b*64+i)*512+d]
// plain stores -> no init needed (poison-safe).
__global__ __launch_bounds__(512)
void reduce_part(const float* __restrict__ x, float* __restrict__ kpart) {
  const int d = threadIdx.x;
  const int b = blockIdx.x;
  float s = 0.f;
#pragma unroll 4
  for (int i = 0; i < 64; i++)
    s += x[((size_t)b * 64 + i) * 512 + d];
  kpart[(size_t)b * 512 + d] = s;
}

// one block, 1024 threads: finish ksum reduction, 16 parallel coarse dots
// (one wave per expert), top-4 select, bias gather. Replaces the 59us
// single-wave gate_topk + bias_gather.
__global__ __launch_bounds__(1024)
void gate_all(const float* __restrict__ kpart,
              const float* __restrict__ gate_w,
              const float* __restrict__ gate_b,
              const float* __restrict__ b1, const float* __restrict__ b2,
              int* __restrict__ idxout,
              float* __restrict__ b1cat, float* __restrict__ b2sel) {
  __shared__ float ksum2[2][512];
  __shared__ float coarse[16];
  __shared__ int idxl[4];
  const int t = threadIdx.x;
  // phase 1: reduce 256 partials (two halves of 128)
  {
    const int d = t & 511, h = t >> 9;
    float s = 0.f;
    for (int p = h * 128; p < h * 128 + 128; p++) s += kpart[(size_t)p * 512 + d];
    ksum2[h][d] = s;
  }
  __syncthreads();
  // phase 2: wave e computes coarse[e] = gate_w[e]·ksum + gate_b[e]
  {
    const int wave = t >> 6, lane = t & 63;
    const int d0 = lane * 8;
    float s = 0.f;
#pragma unroll
    for (int j = 0; j < 8; j++)
      s += gate_w[wave * 512 + d0 + j] * (ksum2[0][d0 + j] + ksum2[1][d0 + j]);
#pragma unroll
    for (int off = 32; off >= 1; off >>= 1) s += __shfl_down(s, off, 64);
    if (lane == 0) coarse[wave] = s + gate_b[wave];
  }
  __syncthreads();
  // phase 3: top-4
  if (t == 0) {
    unsigned taken = 0;
    for (int r = 0; r < 4; r++) {
      float best = -3.4e38f; int bi = 0;
      for (int e = 0; e < 16; e++)
        if (!((taken >> e) & 1u) && coarse[e] > best) { best = coarse[e]; bi = e; }
      taken |= 1u << bi;
      idxl[r] = bi; idxout[r] = bi;
    }
  }
  __syncthreads();
  // phase 4: bias gather
  for (int i = t; i < 8192; i += 1024)
    b1cat[i] = b1[(size_t)idxl[i >> 11] * 2048 + (i & 2047)];
  for (int i = t; i < 2048; i += 1024)
    b2sel[i] = b2[(size_t)idxl[i >> 9] * 512 + (i & 511)];
}

// transpose + fp32->bf16 for both W1 (z<4) and W2 (z>=4) in one launch.
// W1: src [512 x 2048] at idx[e] -> w1t[(e*2048+f)*512 + d]
// W2: src [2048 x 512] at idx[e] -> w2t[d*8192 + e*2048 + f]
__global__ __launch_bounds__(256)
void transpose_all(const float* __restrict__ w1, const float* __restrict__ w2,
                   unsigned short* __restrict__ w1t, unsigned short* __restrict__ w2t,
                   const int* __restrict__ idx) {
  __shared__ float tl[64][65];
  const int tid = threadIdx.x;
  const int ty = tid >> 6, tx = tid & 63;
  const int z = blockIdx.z;
  const float* src; unsigned short* dbase; int C, dstLd, r0, c0;
  if (z < 4) {
    src = w1 + (size_t)idx[z] * 512 * 2048;
    dbase = w1t + (size_t)z * 2048 * 512;
    C = 2048; dstLd = 512;
    r0 = blockIdx.x * 64; c0 = blockIdx.y * 64;   // r in [0,512), c in [0,2048)
  } else {
    src = w2 + (size_t)idx[z - 4] * 2048 * 512;
    dbase = w2t + (size_t)(z - 4) * 2048;
    C = 512; dstLd = 8192;
    r0 = blockIdx.y * 64; c0 = blockIdx.x * 64;   // r in [0,2048), c in [0,512)
  }
#pragma unroll
  for (int i = 0; i < 16; i++) {
    int r = ty * 16 + i;
    tl[r][tx] = src[(size_t)(r0 + r) * C + c0 + tx];
  }
  __syncthreads();
#pragma unroll
  for (int i = 0; i < 16; i++) {
    int rr = ty * 16 + i;
    dbase[(size_t)(c0 + rr) * dstLd + r0 + tx] = f2bf(tl[tx][rr]);
  }
}

// per-token softmax gate over 4 selected experts + x -> bf16
__global__ __launch_bounds__(256)
void gate_softmax_xconv(const float* __restrict__ x,
                        const float* __restrict__ gate_w,
                        const float* __restrict__ gate_b,
                        const int* __restrict__ idx,
                        float* __restrict__ gwout,
                        unsigned short* __restrict__ xbf) {
  __shared__ float wsel[4][512];
  __shared__ float bsel[4];
  const int tid = threadIdx.x;
  for (int i = tid; i < 2048; i += 256) {
    int k = i >> 9;
    wsel[k][i & 511] = gate_w[(size_t)idx[k] * 512 + (i & 511)];
  }
  if (tid < 4) bsel[tid] = gate_b[idx[tid]];
  __syncthreads();
  const int wave = tid >> 6, lane = tid & 63;
  const int t = blockIdx.x * 4 + wave;
  const float* xr = x + (size_t)t * 512 + lane * 8;
  float4 v0 = ((const float4*)xr)[0];
  float4 v1 = ((const float4*)xr)[1];
  float vals[8] = {v0.x, v0.y, v0.z, v0.w, v1.x, v1.y, v1.z, v1.w};
  short8 pk;
#pragma unroll
  for (int j = 0; j < 8; j++) pk[j] = (short)f2bf(vals[j]);
  *(short8*)(xbf + (size_t)t * 512 + lane * 8) = pk;
  float a0 = 0.f, a1 = 0.f, a2 = 0.f, a3 = 0.f;
  const int dbase = lane * 8;
#pragma unroll
  for (int j = 0; j < 8; j++) {
    float xv = vals[j];
    a0 += xv * wsel[0][dbase + j];
    a1 += xv * wsel[1][dbase + j];
    a2 += xv * wsel[2][dbase + j];
    a3 += xv * wsel[3][dbase + j];
  }
#pragma unroll
  for (int off = 32; off >= 1; off >>= 1) {
    a0 += __shfl_down(a0, off, 64);
    a1 += __shfl_down(a1, off, 64);
    a2 += __shfl_down(a2, off, 64);
    a3 += __shfl_down(a3, off, 64);
  }
  if (lane == 0) {
    float l0 = a0 + bsel[0], l1 = a1 + bsel[1], l2 = a2 + bsel[2], l3 = a3 + bsel[3];
    float m = fmaxf(fmaxf(l0, l1), fmaxf(l2, l3));
    float e0 = __expf(l0 - m), e1 = __expf(l1 - m);
    float e2 = __expf(l2 - m), e3 = __expf(l3 - m);
    float inv = 1.0f / (e0 + e1 + e2 + e3);
    float* o = gwout + (size_t)t * 4;
    o[0] = e0 * inv; o[1] = e1 * inv; o[2] = e2 * inv; o[3] = e3 * inv;
  }
}

// ---------------- main GEMM ----------------
// C[M x N] = A[M x K(lda)] * Bt[N x K(ldb)]^T  (bf16, K-contiguous rows)
// 128x128 tile, BK=64, 256 threads, 16x16x32 bf16 MFMA, XOR-swizzled LDS.
// EPI==1: Cb[r*ldc+n] = bf16( gw[r,kexp] * gelu(acc + bias[colOff+n]) )
// EPI==2: Cf[r*512+n] = acc + (accum ? Cf[r*512+n]
//                                    : sum_k gw[r,k]*bias[k*512+n])
template <int EPI>
__global__ __launch_bounds__(256, 2)
void gemm_bt(const unsigned short* __restrict__ A,
             const unsigned short* __restrict__ Bt,
             void* __restrict__ C, int K, int lda, int ldb, int ldc,
             const float* __restrict__ gw,
             const float* __restrict__ bias, int colOff, int accum) {
  __shared__ unsigned short lA[128 * 64];
  __shared__ unsigned short lB[128 * 64];
  const int tid = threadIdx.x;
  const int wave = tid >> 6;
  const int lane = tid & 63;
  const int rowA0 = blockIdx.x * 128;
  const int rowB0 = blockIdx.y * 128;

  f32x4 acc[4][4];
#pragma unroll
  for (int i = 0; i < 4; i++)
#pragma unroll
    for (int j = 0; j < 4; j++) acc[i][j] = (f32x4){0.f, 0.f, 0.f, 0.f};

  const int lrow = lane >> 3;
  const int lslot = lane & 7;
  const int gchunk = lslot ^ lrow;     // store-side XOR swizzle (16B granule)
  const int fr = lane & 15;
  const int quad = lane >> 4;
  const int wm = (wave >> 1) * 64;
  const int wn = (wave & 1) * 64;
  const int swz = fr & 7;

  for (int kt = 0; kt < K; kt += 64) {
#pragma unroll
    for (int c = 0; c < 4; c++) {
      int r = wave * 32 + c * 8 + lrow;
      const unsigned short* gp = A + (size_t)(rowA0 + r) * lda + kt + gchunk * 8;
      __builtin_amdgcn_global_load_lds(AS1U32(gp), AS3U32(lA + (wave * 32 + c * 8) * 64), 16, 0, 0);
    }
#pragma unroll
    for (int c = 0; c < 4; c++) {
      int r = wave * 32 + c * 8 + lrow;
      const unsigned short* gp = Bt + (size_t)(rowB0 + r) * ldb + kt + gchunk * 8;
      __builtin_amdgcn_global_load_lds(AS1U32(gp), AS3U32(lB + (wave * 32 + c * 8) * 64), 16, 0, 0);
    }
    __syncthreads();
#pragma unroll
    for (int ks = 0; ks < 2; ks++) {
      short8 af[4], bfr[4];
      const int c = ks * 4 + quad;
      const int slot = (c ^ swz) << 3;
#pragma unroll
      for (int i = 0; i < 4; i++)
        af[i] = *(const short8*)(lA + (wm + i * 16 + fr) * 64 + slot);
#pragma unroll
      for (int j = 0; j < 4; j++)
        bfr[j] = *(const short8*)(lB + (wn + j * 16 + fr) * 64 + slot);
#pragma unroll
      for (int i = 0; i < 4; i++)
#pragma unroll
        for (int j = 0; j < 4; j++)
          acc[i][j] = __builtin_amdgcn_mfma_f32_16x16x32_bf16(af[i], bfr[j], acc[i][j], 0, 0, 0);
    }
    __syncthreads();
  }

  if (EPI == 1) {
    unsigned short* Cb = (unsigned short*)C;
    const int kexp = (colOff + rowB0) >> 11;
#pragma unroll
    for (int i = 0; i < 4; i++) {
#pragma unroll
      for (int reg = 0; reg < 4; reg++) {
        int r = rowA0 + wm + i * 16 + quad * 4 + reg;
        float g = gw[(size_t)r * 4 + kexp];
#pragma unroll
        for (int j = 0; j < 4; j++) {
          int n = rowB0 + wn + j * 16 + fr;
          float v = acc[i][j][reg] + bias[colOff + n];
          Cb[(size_t)r * ldc + n] = f2bf(gelu_fast(v) * g);
        }
      }
    }
  } else {
    float* Cf = (float*)C;
#pragma unroll
    for (int i = 0; i < 4; i++) {
#pragma unroll
      for (int reg = 0; reg < 4; reg++) {
        int r = rowA0 + wm + i * 16 + quad * 4 + reg;
        size_t t4 = (size_t)r * 4;
        float g0 = gw[t4], g1 = gw[t4 + 1], g2 = gw[t4 + 2], g3 = gw[t4 + 3];
#pragma unroll
        for (int j = 0; j < 4; j++) {
          int n = rowB0 + wn + j * 16 + fr;
          size_t ci = (size_t)r * 512 + n;
          float v = acc[i][j][reg];
          if (accum) v += Cf[ci];
          else v += g0 * bias[n] + g1 * bias[512 + n] +
                    g2 * bias[1024 + n] + g3 * bias[1536 + n];
          Cf[ci] = v;
        }
      }
    }
  }
}

// ---------------- launch ----------------

extern "C" void kernel_launch(void* const* d_in, const int* in_sizes, int n_in,
                              void* d_out, int out_size, void* d_ws, size_t ws_size,
                              hipStream_t stream) {
  (void)in_sizes; (void)n_in; (void)out_size;
  const float* x      = (const float*)d_in[0];
  const float* gate_w = (const float*)d_in[1];
  const float* gate_b = (const float*)d_in[2];
  const float* w1     = (const float*)d_in[3];
  const float* b1     = (const float*)d_in[4];
  const float* w2     = (const float*)d_in[5];
  const float* b2     = (const float*)d_in[6];

  char* ws = (char*)d_ws;
  int*            idx   = (int*)(ws + 0);                //  16 B
  float*          gw    = (float*)(ws + 4096);           // 256 KB  [T,4]
  float*          b1cat = (float*)(ws + 266240);         //  32 KB
  float*          b2sel = (float*)(ws + 299008);         //   8 KB
  float*          kpart = (float*)(ws + 307200);         // 512 KB  [256,512]
  unsigned short* xbf   = (unsigned short*)(ws + 831488);      // 16.8 MB [T,512]
  unsigned short* w1t   = (unsigned short*)(ws + 17608704);    //  8.4 MB [8192,512]
  unsigned short* w2t   = (unsigned short*)(ws + 25997312);    //  8.4 MB [512,8192]
  unsigned short* hbuf  = (unsigned short*)(ws + 34385920);    // h' slab
  const size_t HBUF_OFF = 34385920;

  // DF-slab: h' slab = [16384 x slabDF] bf16. Fewest slabs that fit
  // (each extra slab costs 2 dispatches ~10us each + 67MB out-RMW traffic).
  size_t avail = ws_size > HBUF_OFF ? ws_size - HBUF_OFF : 0;
  int nslab = 1;
  while (nslab < 16 && (size_t)16384 * (8192 / nslab) * 2 > avail) nslab <<= 1;
  const int slabDF = 8192 / nslab;

  reduce_part<<<256, 512, 0, stream>>>(x, kpart);
  gate_all<<<1, 1024, 0, stream>>>(kpart, gate_w, gate_b, b1, b2, idx, b1cat, b2sel);
  transpose_all<<<dim3(8, 32, 8), 256, 0, stream>>>(w1, w2, w1t, w2t, idx);
  gate_softmax_xconv<<<4096, 256, 0, stream>>>(x, gate_w, gate_b, idx, gw, xbf);

  for (int s = 0; s < nslab; s++) {
    const int c0 = s * slabDF;
    gemm_bt<1><<<dim3(128, slabDF / 128), 256, 0, stream>>>(
        xbf, w1t + (size_t)c0 * 512, hbuf,
        /*K=*/512, /*lda=*/512, /*ldb=*/512, /*ldc=*/slabDF,
        gw, b1cat, c0, 0);
    gemm_bt<2><<<dim3(128, 4), 256, 0, stream>>>(
        hbuf, w2t + c0, (float*)d_out,
        /*K=*/slabDF, /*lda=*/slabDF, /*ldb=*/8192, /*ldc=*/512,
        gw, b2sel, 0, s > 0);
  }
}